// Round 15
// baseline (1061.337 us; speedup 1.0000x reference)
//
#include <hip/hip_runtime.h>
#include <math.h>

typedef unsigned int u32;
typedef unsigned short u16;
typedef unsigned char u8;
typedef unsigned long long u64;
typedef int i32x4 __attribute__((ext_vector_type(4)));
typedef int i32x8 __attribute__((ext_vector_type(8)));
typedef float f32x4 __attribute__((ext_vector_type(4)));
typedef float f32x16 __attribute__((ext_vector_type(16)));

#define B_  16
#define S_  2048
#define D_  1024
#define H_  256
#define SD_ 14
#define C_  6
#define G_  3
#define E_  18

typedef union { i32x8 v8; i32x4 v4[2]; } A8;

// hardware fp8 (OCP e4m3 on gfx950) pack: 2 floats -> bytes 0,1 of result
static __device__ __forceinline__ u32 pk8(float a, float b) {
  return (u32)__builtin_amdgcn_cvt_pk_fp8_f32(a, b, 0, false);
}

// ---------------- K3: F f32 -> fp8(x4) + column-mean pooling ----------------
__global__ __launch_bounds__(256) void k_convpool8(const float* __restrict__ F,
                                                   u8* __restrict__ F8,
                                                   float* __restrict__ fsum) {
  const int bb = blockIdx.x >> 5;
  const int sc = blockIdx.x & 31;
  const int t  = threadIdx.x;
  const size_t base = (size_t)(bb * S_ + sc * 64) * D_ + t * 4;
  float s0 = 0.f, s1 = 0.f, s2 = 0.f, s3 = 0.f;
  for (int i = 0; i < 64; ++i) {
    const f32x4 v = *(const f32x4*)(F + base + (size_t)i * D_);
    s0 += v[0]; s1 += v[1]; s2 += v[2]; s3 += v[3];
    const u32 q = pk8(v[0] * 4.f, v[1] * 4.f) | (pk8(v[2] * 4.f, v[3] * 4.f) << 16);
    *(u32*)(F8 + base + (size_t)i * D_) = q;
  }
  const int c = t * 4;
  atomicAdd(&fsum[bb * D_ + c + 0], s0);
  atomicAdd(&fsum[bb * D_ + c + 1], s1);
  atomicAdd(&fsum[bb * D_ + c + 2], s2);
  atomicAdd(&fsum[bb * D_ + c + 3], s3);
}

// ---------------- K3b: pooling only (lean path) ----------------
__global__ __launch_bounds__(256) void k_poolF(const float* __restrict__ F,
                                               float* __restrict__ fsum) {
  const int bb = blockIdx.x >> 5;
  const int sc = blockIdx.x & 31;
  const int t  = threadIdx.x;
  const size_t base = (size_t)(bb * S_ + sc * 64) * D_ + t * 4;
  float s0 = 0.f, s1 = 0.f, s2 = 0.f, s3 = 0.f;
  for (int i = 0; i < 64; ++i) {
    const f32x4 v = *(const f32x4*)(F + base + (size_t)i * D_);
    s0 += v[0]; s1 += v[1]; s2 += v[2]; s3 += v[3];
  }
  const int c = t * 4;
  atomicAdd(&fsum[bb * D_ + c + 0], s0);
  atomicAdd(&fsum[bb * D_ + c + 1], s1);
  atomicAdd(&fsum[bb * D_ + c + 2], s2);
  atomicAdd(&fsum[bb * D_ + c + 3], s3);
}

// ---------------- K1: x_raw column-mean pooling ----------------
__global__ __launch_bounds__(256) void k_xpool(const float* __restrict__ X,
                                               float* __restrict__ xsum) {
  const int b = blockIdx.x;
  const int t = threadIdx.x;
  float ls[SD_];
  #pragma unroll
  for (int c = 0; c < SD_; ++c) ls[c] = 0.f;
  for (int s = t; s < S_; s += 256) {
    const float* row = X + (size_t)(b * S_ + s) * SD_;
    #pragma unroll
    for (int c = 0; c < SD_; ++c) ls[c] += row[c];
  }
  #pragma unroll
  for (int c = 0; c < SD_; ++c) atomicAdd(&xsum[b * SD_ + c], ls[c]);
}

// ---------------- K2: routers + flat weights + expert loads + lb + bias term ----------------
__global__ __launch_bounds__(256) void k_router(const float* __restrict__ fsum,
                                                const float* __restrict__ xsum,
                                                const float* __restrict__ cond_w,
                                                const float* __restrict__ cond_b,
                                                const float* __restrict__ stage_w,
                                                const float* __restrict__ stage_b,
                                                const float* __restrict__ up_b,
                                                float* __restrict__ flatw,
                                                float* __restrict__ biasws,
                                                float* __restrict__ out_tail) {
  __shared__ float s_cl[B_][C_], s_sl[B_][G_];
  __shared__ float s_cw[B_][C_], s_sw[B_][G_];
  __shared__ float s_fw[B_][E_], s_ld[E_];
  const int t = threadIdx.x;
  if (t < B_ * C_) {
    const int b = t / C_, c = t % C_;
    float a = cond_b[c];
    for (int d = 0; d < D_; ++d) a += (fsum[b * D_ + d] * (1.f / S_)) * cond_w[d * C_ + c];
    s_cl[b][c] = a;
  }
  if (t < B_ * G_) {
    const int b = t / G_, g = t % G_;
    float a = stage_b[g];
    for (int sd = 0; sd < SD_; ++sd) a += (xsum[b * SD_ + sd] * (1.f / S_)) * stage_w[sd * G_ + g];
    s_sl[b][g] = a;
  }
  __syncthreads();
  if (t < B_) {
    float m = s_cl[t][0];
    for (int c = 1; c < C_; ++c) m = fmaxf(m, s_cl[t][c]);
    float den = 0.f, ex[C_];
    for (int c = 0; c < C_; ++c) { ex[c] = expf(s_cl[t][c] - m); den += ex[c]; }
    for (int c = 0; c < C_; ++c) s_cw[t][c] = ex[c] / den;
    float m2 = s_sl[t][0];
    for (int g = 1; g < G_; ++g) m2 = fmaxf(m2, s_sl[t][g]);
    float den2 = 0.f, ex2[G_];
    for (int g = 0; g < G_; ++g) { ex2[g] = expf(s_sl[t][g] - m2); den2 += ex2[g]; }
    for (int g = 0; g < G_; ++g) s_sw[t][g] = ex2[g] / den2;
    for (int c = 0; c < C_; ++c)
      for (int g = 0; g < G_; ++g) s_fw[t][c * G_ + g] = s_cw[t][c] * s_sw[t][g];
  }
  __syncthreads();
  if (t < B_ * C_) out_tail[t] = s_cw[t / C_][t % C_];
  if (t < B_ * G_) out_tail[B_ * C_ + t] = s_sw[t / G_][t % G_];
  for (int i = t; i < B_ * E_; i += 256) flatw[i] = s_fw[i / E_][i % E_];
  if (t < E_) {
    float a = 0.f;
    for (int b = 0; b < B_; ++b) a += s_fw[b][t];
    s_ld[t] = a / (float)B_;
    out_tail[B_ * C_ + B_ * G_ + t] = s_ld[t];
  }
  __syncthreads();
  if (t == 0) {
    float a = 0.f;
    for (int e = 0; e < E_; ++e) a += s_ld[e] * s_ld[e];
    out_tail[B_ * C_ + B_ * G_ + E_] = (float)E_ * a * 0.01f;
  }
  for (int i = t; i < B_ * D_; i += 256) {
    const int b = i >> 10, d = i & 1023;
    float a = 0.f;
    #pragma unroll
    for (int e = 0; e < E_; ++e) a += s_fw[b][e] * up_b[e * D_ + d];
    biasws[i] = a;
  }
}

// ---------------- K4: fragmentizer to fp8 for MX 32x32x64 MFMA ----------------
// src [E][K][N] f32 -> dst frag-linear e4m3 [e][kb=K/64][cb=N/32][lane=64][32B]:
//   byte j (0..31) of lane l = e4m3(src[e][kb*64 + (l>>5)*32 + j][cb*32 + (l&31)] * scale)
__global__ __launch_bounds__(256) void k_frag8mx(const float* __restrict__ src,
                                                 u8* __restrict__ dst, int K, int N,
                                                 float scale) {
  const int kgrp = K >> 7;           // 128 k-rows per block
  const int ncb = N >> 5;
  const int bid = blockIdx.x;
  const int kbg = bid % kgrp;
  const int cb  = (bid / kgrp) % ncb;
  const int e   = bid / (kgrp * ncb);
  __shared__ float tile[128][33];
  const int t = threadIdx.x;
  #pragma unroll
  for (int it = 0; it < 16; ++it) {
    const int i = it * 256 + t;
    const int row = i >> 5, col = i & 31;
    tile[row][col] = src[((size_t)e * K + kbg * 128 + row) * N + cb * 32 + col];
  }
  __syncthreads();
  const int lane = t & 63, q = t >> 6;   // q = 0..3
  const int l31 = lane & 31, lhi = lane >> 5;
  const int kbl = q & 1;                 // local kb (64 k-rows each)
  const int jb  = (q >> 1) * 16;         // byte sub-range of the 32B operand
  const int kb  = kbg * 2 + kbl;
  float x[16];
  #pragma unroll
  for (int jj = 0; jj < 16; ++jj)
    x[jj] = tile[kbl * 64 + lhi * 32 + jb + jj][l31] * scale;
  const u32 a0 = pk8(x[0],  x[1])  | (pk8(x[2],  x[3])  << 16);
  const u32 a1 = pk8(x[4],  x[5])  | (pk8(x[6],  x[7])  << 16);
  const u32 a2 = pk8(x[8],  x[9])  | (pk8(x[10], x[11]) << 16);
  const u32 a3 = pk8(x[12], x[13]) | (pk8(x[14], x[15]) << 16);
  u8* dp = dst + ((((size_t)e * (K >> 6) + kb) * ncb + cb) * 64 + lane) * 32 + jb;
  *(u64*)dp       = (u64)a0 | ((u64)a1 << 32);
  *(u64*)(dp + 8) = (u64)a2 | ((u64)a3 << 32);
}

// MX-scaled fp8 MFMA, unit scales (0x7F = 2^0): numerics identical to plain fp8.
#define MFMAMX(a, b, c) \
  __builtin_amdgcn_mfma_scale_f32_32x32x64_f8f6f4((a), (b), (c), 0, 0, 0, 127, 0, 127)

// fast gelu (tanh form via exp2)
static __device__ __forceinline__ float gelu_f(float x) {
  float y2 = 2.302208f * x * (1.f + 0.044715f * x * x);
  y2 = fminf(fmaxf(y2, -30.f), 30.f);
  const float p = __builtin_exp2f(y2);
  return x * p / (p + 1.f);
}

// gelu + routing-scale + fp8-pack + swizzled Hb store (16 values/lane)
static __device__ __forceinline__ void gelu_store(u8* hb, const f32x16& h,
                                                  int hc, float dbv, float sc8, int lhi) {
  const int pg_ = hc >> 4;
  const int lb_ = hc & 15;
  #pragma unroll
  for (int q = 0; q < 4; ++q) {
    float g[4];
    #pragma unroll
    for (int j = 0; j < 4; ++j) {
      const float x = h[q * 4 + j] * 0.015625f + dbv;
      g[j] = gelu_f(x) * sc8;
    }
    const u32 p01 = pk8(g[0], g[1]);
    const u32 p23 = pk8(g[2], g[3]);
    #pragma unroll
    for (int j = 0; j < 4; ++j) {
      const int row = 8 * q + j + 4 * lhi;
      const u8 byte = (u8)((j < 2 ? p01 : p23) >> (8 * (j & 1)));
      hb[row * 256 + (((pg_ ^ (row & 15)) << 4) | lb_)] = byte;
    }
  }
}

// up-B frag byte offset for pipeline step j (half=(j>>3), ks=(j>>1)&3, cb=(j>>3)*2+(j&1))
static __device__ __forceinline__ int ub_off(int j) {
  return ((j >> 1) & 3) * 65536 + ((j >> 3) * 2 + (j & 1)) * 2048;
}

// ---------------- K5: fused MoE main kernel (v15 = v14 phase-merge, reg-lite) ----------------
// v14's merge spilled (~35 regs over). v15 cuts demand below the 256-reg wall:
// single hacc chain (-16; the down chain alternates with independent up MFMAs,
// plus 2 waves/SIMD -> pipe stays fed), ubd depth 4 (+16 but fixes v14's
// 137-cyc up-B cover < L2 latency). Tally: acc 64 + hacc 16 + pb 32 + a 16 +
// ua 16 + ubd 32 = 176 + ~40 temps ~= 216 < 256. Same barrier/Hb-dbuf
// correctness as v13. Spill canary: WRITE_SIZE must be exactly 131072 KB.
template<int LEAN>
__global__ __launch_bounds__(512, 2) void k_moe(const u8* __restrict__ F8,
                                                const float* __restrict__ Ff32,
                                                const u8* __restrict__ dwF8,   // [e][16kb][8cb][64][32B]
                                                const u8* __restrict__ uwF8,   // [e][4kb][32cb][64][32B]
                                                const float* __restrict__ down_b,
                                                const float* __restrict__ flatw,
                                                const float* __restrict__ biasws,
                                                float* __restrict__ out) {
  __shared__ u8 Fb[32 * 1024];     // 32 KiB; row=1024B = 64 granules x 16B
  __shared__ u8 Hb[2][32 * 256];   // 2 x 8 KiB; row=256B = 16 granules x 16B

  const int tile = blockIdx.x;
  const int r0 = tile * 32;
  const int b = r0 >> 11;
  const int t = threadIdx.x;
  const int w = t >> 6;            // 0..7
  const int l = t & 63;
  const int l31 = l & 31;
  const int lhi = l >> 5;          // 0..1
  const int lhi2 = lhi * 2;
  const int r15 = l31 & 15;

  // ---- stage F tile (fp8), 16B-granule XOR swizzle ----
  #pragma unroll
  for (int i = 0; i < 8; ++i) {
    const int idx = i * 512 + t;     // 4096 8B-units
    const int row = idx >> 7;        // 0..31
    const int o8  = idx & 127;
    u64 v;
    if constexpr (!LEAN) {
      v = *(const u64*)(F8 + (size_t)(r0 + row) * D_ + o8 * 8);
    } else {
      const float* src = Ff32 + (size_t)(r0 + row) * D_ + o8 * 8;
      const u32 lo = pk8(src[0] * 4.f, src[1] * 4.f) | (pk8(src[2] * 4.f, src[3] * 4.f) << 16);
      const u32 hi = pk8(src[4] * 4.f, src[5] * 4.f) | (pk8(src[6] * 4.f, src[7] * 4.f) << 16);
      v = (u64)lo | ((u64)hi << 32);
    }
    const int adr = row * 1024 + ((((o8 >> 1) ^ (row & 15)) << 4) | ((o8 & 1) << 3));
    *(u64*)(Fb + adr) = v;
  }

  // bases
  const u8* dB = dwF8 + ((size_t)w * 64 + l) * 32;              // cb=w; kb stride 16384; e stride 262144
  const size_t ulane = ((size_t)(4 * w) * 64 + l) * 32;          // up: cb base 4w
  const u8* fbb = Fb + l31 * 1024;

  // preload expert-0 down-B, depth 4 (kb=0..3)
  i32x8 pb[4];
  #pragma unroll
  for (int p = 0; p < 4; ++p)
    pb[p] = *(const i32x8*)(dB + (size_t)p * 16384);

  f32x16 acc[4];
  #pragma unroll
  for (int j = 0; j < 4; ++j)
    #pragma unroll
    for (int i = 0; i < 16; ++i) acc[j][i] = 0.f;

  i32x8 ubd[4];

  __syncthreads();

  const float* fwb = flatw + b * E_;

  // ================= prologue: down(0) only =================
  {
    f32x16 hacc;
    #pragma unroll
    for (int i = 0; i < 16; ++i) hacc[i] = 0.f;
    A8 a[2];
    a[0].v4[0] = *(const i32x4*)(fbb + (((lhi2 + 0) ^ r15) << 4));
    a[0].v4[1] = *(const i32x4*)(fbb + (((lhi2 + 1) ^ r15) << 4));
    #pragma unroll
    for (int i = 0; i < 16; ++i) {
      const int cur = i & 1, nxt = cur ^ 1;
      if (i < 15) {
        const int g0 = (i + 1) * 4 + lhi2;
        a[nxt].v4[0] = *(const i32x4*)(fbb + (((g0 + 0) ^ r15) << 4));
        a[nxt].v4[1] = *(const i32x4*)(fbb + (((g0 + 1) ^ r15) << 4));
      }
      const i32x8 bb = pb[i & 3];
      if (i < 12) pb[i & 3] = *(const i32x8*)(dB + (size_t)(i + 4) * 16384);
      hacc = MFMAMX(a[cur].v8, bb, hacc);
    }
    // tail: ubd[0..3] for up(0); pb for down(1); gelu(0); barrier
    #pragma unroll
    for (int j = 0; j < 4; ++j)
      ubd[j] = *(const i32x8*)(uwF8 + ulane + ub_off(j));
    {
      const u8* dBn = dB + (size_t)1 * 262144;
      #pragma unroll
      for (int p = 0; p < 4; ++p) pb[p] = *(const i32x8*)(dBn + (size_t)p * 16384);
    }
    const int hc = w * 32 + l31;
    gelu_store(Hb[0], hacc, hc, down_b[hc], 8.f * fwb[0], lhi);
    __syncthreads();
  }

  // ================= main loop: up(e-1) interleaved with down(e) =================
  #pragma unroll 1
  for (int e = 1; e < E_; ++e) {
    const int ep = e - 1;
    const u8* hbb = Hb[ep & 1] + l31 * 256;
    const u8* dBe = dB + (size_t)e * 262144;
    const u8* uBp = uwF8 + (size_t)ep * 262144 + ulane;

    f32x16 hacc;
    #pragma unroll
    for (int i = 0; i < 16; ++i) hacc[i] = 0.f;

    A8 a[2], ua[2];
    a[0].v4[0]  = *(const i32x4*)(fbb + (((lhi2 + 0) ^ r15) << 4));
    a[0].v4[1]  = *(const i32x4*)(fbb + (((lhi2 + 1) ^ r15) << 4));
    ua[0].v4[0] = *(const i32x4*)(hbb + (((lhi2 + 0) ^ r15) << 4));
    ua[0].v4[1] = *(const i32x4*)(hbb + (((lhi2 + 1) ^ r15) << 4));

    #pragma unroll
    for (int i = 0; i < 16; ++i) {
      const int cur = i & 1, nxt = cur ^ 1;
      // down A prefetch (LDS)
      if (i < 15) {
        const int g0 = (i + 1) * 4 + lhi2;
        a[nxt].v4[0] = *(const i32x4*)(fbb + (((g0 + 0) ^ r15) << 4));
        a[nxt].v4[1] = *(const i32x4*)(fbb + (((g0 + 1) ^ r15) << 4));
      }
      // down B rolling refill (global, 4 deep)
      const i32x8 bb = pb[i & 3];
      if (i < 12) pb[i & 3] = *(const i32x8*)(dBe + (size_t)(i + 4) * 16384);
      // up A prefetch (LDS): p = i>>1 indexes (half,ks); ua depends on ks = p&3
      if (((i & 1) == 0) && i < 14) {
        const int p1 = (i >> 1) + 1;
        const int g0 = (p1 & 3) * 4 + lhi2;
        ua[p1 & 1].v4[0] = *(const i32x4*)(hbb + (((g0 + 0) ^ r15) << 4));
        ua[p1 & 1].v4[1] = *(const i32x4*)(hbb + (((g0 + 1) ^ r15) << 4));
      }
      // up B rolling refill (global, 4 deep)
      const i32x8 ubv = ubd[i & 3];
      if (i < 12) ubd[i & 3] = *(const i32x8*)(uBp + ub_off(i + 4));
      // the two independent MFMA streams
      hacc = MFMAMX(a[cur].v8, bb, hacc);
      acc[(i >> 3) * 2 + (i & 1)] =
          MFMAMX(ua[(i >> 1) & 1].v8, ubv, acc[(i >> 3) * 2 + (i & 1)]);
    }

    // tail: ubd[0..3] for up(e); pb for down(e+1); gelu(e); barrier
    const u8* uBn = uwF8 + (size_t)e * 262144 + ulane;
    #pragma unroll
    for (int j = 0; j < 4; ++j)
      ubd[j] = *(const i32x8*)(uBn + ub_off(j));
    if (e + 1 < E_) {
      const u8* dBn = dB + (size_t)(e + 1) * 262144;
      #pragma unroll
      for (int p = 0; p < 4; ++p) pb[p] = *(const i32x8*)(dBn + (size_t)p * 16384);
    }
    const int hc = w * 32 + l31;
    gelu_store(Hb[e & 1], hacc, hc, down_b[e * H_ + hc], 8.f * fwb[e], lhi);
    __syncthreads();
  }

  // ================= epilogue: up(17) standalone =================
  {
    const u8* hbb = Hb[(E_ - 1) & 1] + l31 * 256;
    const u8* uBp = uwF8 + (size_t)(E_ - 1) * 262144 + ulane;
    A8 ua[2];
    ua[0].v4[0] = *(const i32x4*)(hbb + (((lhi2 + 0) ^ r15) << 4));
    ua[0].v4[1] = *(const i32x4*)(hbb + (((lhi2 + 1) ^ r15) << 4));
    #pragma unroll
    for (int i = 0; i < 16; ++i) {
      if (((i & 1) == 0) && i < 14) {
        const int p1 = (i >> 1) + 1;
        const int g0 = (p1 & 3) * 4 + lhi2;
        ua[p1 & 1].v4[0] = *(const i32x4*)(hbb + (((g0 + 0) ^ r15) << 4));
        ua[p1 & 1].v4[1] = *(const i32x4*)(hbb + (((g0 + 1) ^ r15) << 4));
      }
      const i32x8 ubv = ubd[i & 3];
      if (i < 12) ubd[i & 3] = *(const i32x8*)(uBp + ub_off(i + 4));
      acc[(i >> 3) * 2 + (i & 1)] =
          MFMAMX(ua[(i >> 1) & 1].v8, ubv, acc[(i >> 3) * 2 + (i & 1)]);
    }
  }

  // ---- epilogue: residual + bias + store; /128 undoes h(x8)*uw(x16) ----
  const float* bias = biasws + b * D_;
  #pragma unroll
  for (int fc = 0; fc < 4; ++fc) {
    const int col = w * 128 + fc * 32 + l31;
    const float bv = bias[col];
    #pragma unroll
    for (int r = 0; r < 16; ++r) {
      const int row = (r & 3) + 8 * (r >> 2) + 4 * lhi;
      const size_t idx = (size_t)(r0 + row) * D_ + col;
      out[idx] = acc[fc][r] * 0.0078125f + Ff32[idx] + bv;
    }
  }
}

extern "C" void kernel_launch(void* const* d_in, const int* in_sizes, int n_in,
                              void* d_out, int out_size, void* d_ws, size_t ws_size,
                              hipStream_t stream) {
  const float* F  = (const float*)d_in[0];
  const float* X  = (const float*)d_in[1];
  const float* dw = (const float*)d_in[2];
  const float* db = (const float*)d_in[3];
  const float* uw = (const float*)d_in[4];
  const float* ub = (const float*)d_in[5];
  const float* cw = (const float*)d_in[6];
  const float* cb = (const float*)d_in[7];
  const float* sw = (const float*)d_in[8];
  const float* sb = (const float*)d_in[9];
  float* out = (float*)d_out;

  char* ws = (char*)d_ws;
  float* fsum  = (float*)ws;                 // B*D
  float* xsum  = fsum + B_ * D_;             // B*SD
  float* flatw = xsum + B_ * SD_;            // B*E
  float* biasws = flatw + B_ * E_;           // B*D
  size_t off = (size_t)(B_ * D_ + B_ * SD_ + B_ * E_ + B_ * D_) * 4;
  off = (off + 255) & ~(size_t)255;
  u8* dwF8 = (u8*)(ws + off); off += (size_t)E_ * H_ * D_;
  u8* uwF8 = (u8*)(ws + off); off += (size_t)E_ * D_ * H_;
  const size_t need_lean = off;
  u8* F8 = (u8*)(ws + off); off += (size_t)B_ * S_ * D_;
  const size_t need_full = off;

  if (ws_size < need_lean) return;
  const bool lean = ws_size < need_full;

  hipMemsetAsync(d_ws, 0, (size_t)(B_ * D_ + B_ * SD_) * sizeof(float), stream);
  // dw [E][D=K][H=N] x16 ; uw [E][H=K][D=N] x16  (MX 32x32x64 frag layout)
  k_frag8mx<<<E_ * (D_ / 128) * (H_ / 32), 256, 0, stream>>>(dw, dwF8, D_, H_, 16.f);
  k_frag8mx<<<E_ * (H_ / 128) * (D_ / 32), 256, 0, stream>>>(uw, uwF8, H_, D_, 16.f);
  if (!lean) {
    k_convpool8<<<512, 256, 0, stream>>>(F, F8, fsum);
  } else {
    k_poolF<<<512, 256, 0, stream>>>(F, fsum);
  }
  k_xpool<<<B_, 256, 0, stream>>>(X, xsum);
  k_router<<<1, 256, 0, stream>>>(fsum, xsum, cw, cb, sw, sb, ub, flatw, biasws,
                                  out + (size_t)B_ * S_ * D_);
  if (!lean) {
    k_moe<0><<<1024, 512, 0, stream>>>(F8, F, dwF8, uwF8, db, flatw, biasws, out);
  } else {
    k_moe<1><<<1024, 512, 0, stream>>>(nullptr, F, dwF8, uwF8, db, flatw, biasws, out);
  }
}

// Round 16
// 716.847 us; speedup vs baseline: 1.4806x; 1.4806x over previous
//
#include <hip/hip_runtime.h>
#include <math.h>

typedef unsigned int u32;
typedef unsigned short u16;
typedef unsigned char u8;
typedef unsigned long long u64;
typedef long i64;
typedef int i32x4 __attribute__((ext_vector_type(4)));
typedef int i32x8 __attribute__((ext_vector_type(8)));
typedef float f32x4 __attribute__((ext_vector_type(4)));
typedef float f32x16 __attribute__((ext_vector_type(16)));

#define B_  16
#define S_  2048
#define D_  1024
#define H_  256
#define SD_ 14
#define C_  6
#define G_  3
#define E_  18

// hardware fp8 (OCP e4m3 on gfx950) pack: 2 floats -> bytes 0,1 of result
static __device__ __forceinline__ u32 pk8(float a, float b) {
  return (u32)__builtin_amdgcn_cvt_pk_fp8_f32(a, b, 0, false);
}

// ---------------- K3: F f32 -> fp8(x4) + column-mean pooling ----------------
__global__ __launch_bounds__(256) void k_convpool8(const float* __restrict__ F,
                                                   u8* __restrict__ F8,
                                                   float* __restrict__ fsum) {
  const int bb = blockIdx.x >> 5;
  const int sc = blockIdx.x & 31;
  const int t  = threadIdx.x;
  const size_t base = (size_t)(bb * S_ + sc * 64) * D_ + t * 4;
  float s0 = 0.f, s1 = 0.f, s2 = 0.f, s3 = 0.f;
  for (int i = 0; i < 64; ++i) {
    const f32x4 v = *(const f32x4*)(F + base + (size_t)i * D_);
    s0 += v[0]; s1 += v[1]; s2 += v[2]; s3 += v[3];
    const u32 q = pk8(v[0] * 4.f, v[1] * 4.f) | (pk8(v[2] * 4.f, v[3] * 4.f) << 16);
    *(u32*)(F8 + base + (size_t)i * D_) = q;
  }
  const int c = t * 4;
  atomicAdd(&fsum[bb * D_ + c + 0], s0);
  atomicAdd(&fsum[bb * D_ + c + 1], s1);
  atomicAdd(&fsum[bb * D_ + c + 2], s2);
  atomicAdd(&fsum[bb * D_ + c + 3], s3);
}

// ---------------- K3b: pooling only (lean path) ----------------
__global__ __launch_bounds__(256) void k_poolF(const float* __restrict__ F,
                                               float* __restrict__ fsum) {
  const int bb = blockIdx.x >> 5;
  const int sc = blockIdx.x & 31;
  const int t  = threadIdx.x;
  const size_t base = (size_t)(bb * S_ + sc * 64) * D_ + t * 4;
  float s0 = 0.f, s1 = 0.f, s2 = 0.f, s3 = 0.f;
  for (int i = 0; i < 64; ++i) {
    const f32x4 v = *(const f32x4*)(F + base + (size_t)i * D_);
    s0 += v[0]; s1 += v[1]; s2 += v[2]; s3 += v[3];
  }
  const int c = t * 4;
  atomicAdd(&fsum[bb * D_ + c + 0], s0);
  atomicAdd(&fsum[bb * D_ + c + 1], s1);
  atomicAdd(&fsum[bb * D_ + c + 2], s2);
  atomicAdd(&fsum[bb * D_ + c + 3], s3);
}

// ---------------- K1: x_raw column-mean pooling ----------------
__global__ __launch_bounds__(256) void k_xpool(const float* __restrict__ X,
                                               float* __restrict__ xsum) {
  const int b = blockIdx.x;
  const int t = threadIdx.x;
  float ls[SD_];
  #pragma unroll
  for (int c = 0; c < SD_; ++c) ls[c] = 0.f;
  for (int s = t; s < S_; s += 256) {
    const float* row = X + (size_t)(b * S_ + s) * SD_;
    #pragma unroll
    for (int c = 0; c < SD_; ++c) ls[c] += row[c];
  }
  #pragma unroll
  for (int c = 0; c < SD_; ++c) atomicAdd(&xsum[b * SD_ + c], ls[c]);
}

// ---------------- K2: routers + flat weights + expert loads + lb + bias term ----------------
__global__ __launch_bounds__(256) void k_router(const float* __restrict__ fsum,
                                                const float* __restrict__ xsum,
                                                const float* __restrict__ cond_w,
                                                const float* __restrict__ cond_b,
                                                const float* __restrict__ stage_w,
                                                const float* __restrict__ stage_b,
                                                const float* __restrict__ up_b,
                                                float* __restrict__ flatw,
                                                float* __restrict__ biasws,
                                                float* __restrict__ out_tail) {
  __shared__ float s_cl[B_][C_], s_sl[B_][G_];
  __shared__ float s_cw[B_][C_], s_sw[B_][G_];
  __shared__ float s_fw[B_][E_], s_ld[E_];
  const int t = threadIdx.x;
  if (t < B_ * C_) {
    const int b = t / C_, c = t % C_;
    float a = cond_b[c];
    for (int d = 0; d < D_; ++d) a += (fsum[b * D_ + d] * (1.f / S_)) * cond_w[d * C_ + c];
    s_cl[b][c] = a;
  }
  if (t < B_ * G_) {
    const int b = t / G_, g = t % G_;
    float a = stage_b[g];
    for (int sd = 0; sd < SD_; ++sd) a += (xsum[b * SD_ + sd] * (1.f / S_)) * stage_w[sd * G_ + g];
    s_sl[b][g] = a;
  }
  __syncthreads();
  if (t < B_) {
    float m = s_cl[t][0];
    for (int c = 1; c < C_; ++c) m = fmaxf(m, s_cl[t][c]);
    float den = 0.f, ex[C_];
    for (int c = 0; c < C_; ++c) { ex[c] = expf(s_cl[t][c] - m); den += ex[c]; }
    for (int c = 0; c < C_; ++c) s_cw[t][c] = ex[c] / den;
    float m2 = s_sl[t][0];
    for (int g = 1; g < G_; ++g) m2 = fmaxf(m2, s_sl[t][g]);
    float den2 = 0.f, ex2[G_];
    for (int g = 0; g < G_; ++g) { ex2[g] = expf(s_sl[t][g] - m2); den2 += ex2[g]; }
    for (int g = 0; g < G_; ++g) s_sw[t][g] = ex2[g] / den2;
    for (int c = 0; c < C_; ++c)
      for (int g = 0; g < G_; ++g) s_fw[t][c * G_ + g] = s_cw[t][c] * s_sw[t][g];
  }
  __syncthreads();
  if (t < B_ * C_) out_tail[t] = s_cw[t / C_][t % C_];
  if (t < B_ * G_) out_tail[B_ * C_ + t] = s_sw[t / G_][t % G_];
  for (int i = t; i < B_ * E_; i += 256) flatw[i] = s_fw[i / E_][i % E_];
  if (t < E_) {
    float a = 0.f;
    for (int b = 0; b < B_; ++b) a += s_fw[b][t];
    s_ld[t] = a / (float)B_;
    out_tail[B_ * C_ + B_ * G_ + t] = s_ld[t];
  }
  __syncthreads();
  if (t == 0) {
    float a = 0.f;
    for (int e = 0; e < E_; ++e) a += s_ld[e] * s_ld[e];
    out_tail[B_ * C_ + B_ * G_ + E_] = (float)E_ * a * 0.01f;
  }
  for (int i = t; i < B_ * D_; i += 256) {
    const int b = i >> 10, d = i & 1023;
    float a = 0.f;
    #pragma unroll
    for (int e = 0; e < E_; ++e) a += s_fw[b][e] * up_b[e * D_ + d];
    biasws[i] = a;
  }
}

// ---------------- K4: fragmentizer to fp8 for MX 32x32x64 MFMA ----------------
// src [E][K][N] f32 -> dst frag-linear e4m3 [e][kb=K/64][cb=N/32][lane=64][32B]:
//   byte j (0..31) of lane l = e4m3(src[e][kb*64 + (l>>5)*32 + j][cb*32 + (l&31)] * scale)
__global__ __launch_bounds__(256) void k_frag8mx(const float* __restrict__ src,
                                                 u8* __restrict__ dst, int K, int N,
                                                 float scale) {
  const int kgrp = K >> 7;           // 128 k-rows per block
  const int ncb = N >> 5;
  const int bid = blockIdx.x;
  const int kbg = bid % kgrp;
  const int cb  = (bid / kgrp) % ncb;
  const int e   = bid / (kgrp * ncb);
  __shared__ float tile[128][33];
  const int t = threadIdx.x;
  #pragma unroll
  for (int it = 0; it < 16; ++it) {
    const int i = it * 256 + t;
    const int row = i >> 5, col = i & 31;
    tile[row][col] = src[((size_t)e * K + kbg * 128 + row) * N + cb * 32 + col];
  }
  __syncthreads();
  const int lane = t & 63, q = t >> 6;   // q = 0..3
  const int l31 = lane & 31, lhi = lane >> 5;
  const int kbl = q & 1;                 // local kb (64 k-rows each)
  const int jb  = (q >> 1) * 16;         // byte sub-range of the 32B operand
  const int kb  = kbg * 2 + kbl;
  float x[16];
  #pragma unroll
  for (int jj = 0; jj < 16; ++jj)
    x[jj] = tile[kbl * 64 + lhi * 32 + jb + jj][l31] * scale;
  const u32 a0 = pk8(x[0],  x[1])  | (pk8(x[2],  x[3])  << 16);
  const u32 a1 = pk8(x[4],  x[5])  | (pk8(x[6],  x[7])  << 16);
  const u32 a2 = pk8(x[8],  x[9])  | (pk8(x[10], x[11]) << 16);
  const u32 a3 = pk8(x[12], x[13]) | (pk8(x[14], x[15]) << 16);
  u8* dp = dst + ((((size_t)e * (K >> 6) + kb) * ncb + cb) * 64 + lane) * 32 + jb;
  *(u64*)dp       = (u64)a0 | ((u64)a1 << 32);
  *(u64*)(dp + 8) = (u64)a2 | ((u64)a3 << 32);
}

// MX-scaled fp8 MFMA, unit scales (0x7F = 2^0): numerics identical to plain fp8.
#define MFMAMX(a, b, c) \
  __builtin_amdgcn_mfma_scale_f32_32x32x64_f8f6f4((a), (b), (c), 0, 0, 0, 127, 0, 127)

// fast gelu (tanh form via exp2)
static __device__ __forceinline__ float gelu_f(float x) {
  float y2 = 2.302208f * x * (1.f + 0.044715f * x * x);
  y2 = fminf(fmaxf(y2, -30.f), 30.f);
  const float p = __builtin_exp2f(y2);
  return x * p / (p + 1.f);
}

// ---------------- K5: fused MoE main kernel (v13 REVERT: best verified, 626us) ----------------
// BM=32, 512 thr / 8 waves, 2 waves/SIMD (256-reg total budget). MX fp8 K=64:
// 2x MFMA rate, 4x FLOP/instr -> 32 MFMA/wave/expert. Rounds 14/15 proved the
// up||down phase-merge needs ~290 regs -> unavoidable spill at this occupancy;
// v13's phase-sequential schedule is the register-feasible optimum found.
template<int LEAN>
__global__ __launch_bounds__(512, 2) void k_moe(const u8* __restrict__ F8,
                                                const float* __restrict__ Ff32,
                                                const u8* __restrict__ dwF8,   // [e][16kb][8cb][64][32B]
                                                const u8* __restrict__ uwF8,   // [e][4kb][32cb][64][32B]
                                                const float* __restrict__ down_b,
                                                const float* __restrict__ flatw,
                                                const float* __restrict__ biasws,
                                                float* __restrict__ out) {
  __shared__ u8 Fb[32 * 1024];     // 32 KiB; row=1024B = 64 granules x 16B
  __shared__ u8 Hb[2][32 * 256];   // 2 x 8 KiB; row=256B = 16 granules x 16B

  const int tile = blockIdx.x;
  const int r0 = tile * 32;
  const int b = r0 >> 11;
  const int t = threadIdx.x;
  const int w = t >> 6;            // 0..7
  const int l = t & 63;
  const int l31 = l & 31;
  const int lhi = l >> 5;          // 0..1
  const int r15 = l31 & 15;

  // ---- stage F tile (fp8), 16B-granule XOR swizzle ----
  #pragma unroll
  for (int i = 0; i < 8; ++i) {
    const int idx = i * 512 + t;     // 4096 8B-units
    const int row = idx >> 7;        // 0..31
    const int o8  = idx & 127;
    u64 v;
    if constexpr (!LEAN) {
      v = *(const u64*)(F8 + (size_t)(r0 + row) * D_ + o8 * 8);
    } else {
      const float* src = Ff32 + (size_t)(r0 + row) * D_ + o8 * 8;
      const u32 lo = pk8(src[0] * 4.f, src[1] * 4.f) | (pk8(src[2] * 4.f, src[3] * 4.f) << 16);
      const u32 hi = pk8(src[4] * 4.f, src[5] * 4.f) | (pk8(src[6] * 4.f, src[7] * 4.f) << 16);
      v = (u64)lo | ((u64)hi << 32);
    }
    const int adr = row * 1024 + ((((o8 >> 1) ^ (row & 15)) << 4) | ((o8 & 1) << 3));
    *(u64*)(Fb + adr) = v;
  }

  // down-B base: cb = w; kb stride = 8cb*64lane*32B = 16384; e stride = 16kb = 262144
  const u8* dB = dwF8 + ((size_t)w * 64 + l) * 32;

  // preload expert-0 down-B, depth 4 (kb=0..3)
  i32x8 pb[4];
  #pragma unroll
  for (int p = 0; p < 4; ++p)
    pb[p] = *(const i32x8*)(dB + (size_t)p * 16384);

  f32x16 acc[4];
  #pragma unroll
  for (int j = 0; j < 4; ++j)
    #pragma unroll
    for (int i = 0; i < 16; ++i) acc[j][i] = 0.f;

  __syncthreads();

  const float* fwb = flatw + b * E_;

  #pragma unroll 1
  for (int e = 0; e < E_; ++e) {
    u8* hb = Hb[e & 1];
    const u8* dBe = dB + (size_t)e * 262144;

    // ---- DOWN: h[32 x 32cols/wave] = F(32x1024) @ dw[e], 16 k-steps of 64 ----
    f32x16 hacc0, hacc1;   // even/odd-kstep chains
    #pragma unroll
    for (int i = 0; i < 16; ++i) { hacc0[i] = 0.f; hacc1[i] = 0.f; }
    i32x8 a[2];
    {
      const int g0 = lhi * 2;
      const i32x4 lo = *(const i32x4*)(Fb + l31 * 1024 + ((g0 ^ r15) << 4));
      const i32x4 hi = *(const i32x4*)(Fb + l31 * 1024 + (((g0 + 1) ^ r15) << 4));
      a[0] = __builtin_shufflevector(lo, hi, 0, 1, 2, 3, 4, 5, 6, 7);
    }
    #pragma unroll
    for (int kb = 0; kb < 16; ++kb) {
      const int cur = kb & 1, nxt = cur ^ 1;
      if (kb < 15) {
        const int g0 = (kb + 1) * 4 + lhi * 2;
        const i32x4 lo = *(const i32x4*)(Fb + l31 * 1024 + ((g0 ^ r15) << 4));
        const i32x4 hi = *(const i32x4*)(Fb + l31 * 1024 + (((g0 + 1) ^ r15) << 4));
        a[nxt] = __builtin_shufflevector(lo, hi, 0, 1, 2, 3, 4, 5, 6, 7);
      }
      const i32x8 bb = pb[kb & 3];
      if (kb < 12)
        pb[kb & 3] = *(const i32x8*)(dBe + (size_t)(kb + 4) * 16384);
      if (cur == 0) hacc0 = MFMAMX(a[cur], bb, hacc0);
      else          hacc1 = MFMAMX(a[cur], bb, hacc1);
    }

    // ---- up-B (half0, ks=0) preload, then gelu -> Hb[e&1] ----
    // uw layout: frag (kb, cb) at ((kb*32 + cb)*64 + l)*32; wave covers cb = 4w..4w+3
    const u8* uBe = uwF8 + (size_t)e * 262144 + ((size_t)(4 * w) * 64 + l) * 32;
    i32x8 ub[2][2];
    ub[0][0] = *(const i32x8*)(uBe);
    ub[0][1] = *(const i32x8*)(uBe + 2048);

    const float wbe = fwb[e];
    {
      const int hc = w * 32 + l31;               // this lane's h-col
      const float dbv = down_b[e * H_ + hc];
      const float sc8 = 8.f * wbe;
      const int pg_ = hc >> 4;                   // granule of col
      const int lb_ = hc & 15;
      #pragma unroll
      for (int q = 0; q < 4; ++q) {              // reg quads: rows 8q + {0..3} + 4*lhi
        float g[4];
        #pragma unroll
        for (int j = 0; j < 4; ++j) {
          const float x = (hacc0[q * 4 + j] + hacc1[q * 4 + j]) * 0.015625f + dbv;
          g[j] = gelu_f(x) * sc8;
        }
        const u32 p01 = pk8(g[0], g[1]);
        const u32 p23 = pk8(g[2], g[3]);
        #pragma unroll
        for (int j = 0; j < 4; ++j) {
          const int row = 8 * q + j + 4 * lhi;
          const u8 byte = (u8)((j < 2 ? p01 : p23) >> (8 * (j & 1)));
          hb[row * 256 + (((pg_ ^ (row & 15)) << 4) | lb_)] = byte;
        }
      }
    }

    // single barrier/expert: publishes Hb[e&1]; up(e) reads it while gelu(e+1)
    // writes the OTHER buffer; up(e+1) gated by barrier(e+1).
    __syncthreads();

    // next-expert down-B prefetch AFTER the barrier: overlaps the whole up
    // phase instead of being drained by the barrier's vmcnt(0).
    if (e + 1 < E_) {
      const u8* dBn = dB + (size_t)(e + 1) * 262144;
      #pragma unroll
      for (int p = 0; p < 4; ++p)
        pb[p] = *(const i32x8*)(dBn + (size_t)p * 16384);
    }

    // ---- UP: acc[32 x 128cols/wave] += Hb(32x256) @ uw[e]; 2 fc-halves x 4 ksteps ----
    #pragma unroll
    for (int half = 0; half < 2; ++half) {
      i32x8 ua[2];
      {
        const int g0 = lhi * 2;
        const i32x4 lo = *(const i32x4*)(hb + l31 * 256 + ((g0 ^ r15) << 4));
        const i32x4 hi = *(const i32x4*)(hb + l31 * 256 + (((g0 + 1) ^ r15) << 4));
        ua[0] = __builtin_shufflevector(lo, hi, 0, 1, 2, 3, 4, 5, 6, 7);
      }
      #pragma unroll
      for (int ks = 0; ks < 4; ++ks) {
        const int cur = ks & 1, nxt = cur ^ 1;
        if (ks < 3) {
          const int g0 = (ks + 1) * 4 + lhi * 2;
          const i32x4 lo = *(const i32x4*)(hb + l31 * 256 + ((g0 ^ r15) << 4));
          const i32x4 hi = *(const i32x4*)(hb + l31 * 256 + (((g0 + 1) ^ r15) << 4));
          ua[nxt] = __builtin_shufflevector(lo, hi, 0, 1, 2, 3, 4, 5, 6, 7);
          ub[nxt][0] = *(const i32x8*)(uBe + (size_t)(ks + 1) * 65536 + (size_t)(half * 2) * 2048);
          ub[nxt][1] = *(const i32x8*)(uBe + (size_t)(ks + 1) * 65536 + (size_t)(half * 2 + 1) * 2048);
        } else if (half == 0) {
          ub[nxt][0] = *(const i32x8*)(uBe + (size_t)2 * 2048);           // half1, ks0
          ub[nxt][1] = *(const i32x8*)(uBe + (size_t)3 * 2048);
        }
        acc[half * 2 + 0] = MFMAMX(ua[cur], ub[cur][0], acc[half * 2 + 0]);
        acc[half * 2 + 1] = MFMAMX(ua[cur], ub[cur][1], acc[half * 2 + 1]);
      }
    }
  }

  // ---- epilogue: residual + bias + store; /128 undoes h(x8)*uw(x16) ----
  const float* bias = biasws + b * D_;
  #pragma unroll
  for (int fc = 0; fc < 4; ++fc) {
    const int col = w * 128 + fc * 32 + l31;
    const float bv = bias[col];
    #pragma unroll
    for (int r = 0; r < 16; ++r) {
      const int row = (r & 3) + 8 * (r >> 2) + 4 * lhi;
      const size_t idx = (size_t)(r0 + row) * D_ + col;
      out[idx] = acc[fc][r] * 0.0078125f + Ff32[idx] + bv;
    }
  }
}

extern "C" void kernel_launch(void* const* d_in, const int* in_sizes, int n_in,
                              void* d_out, int out_size, void* d_ws, size_t ws_size,
                              hipStream_t stream) {
  const float* F  = (const float*)d_in[0];
  const float* X  = (const float*)d_in[1];
  const float* dw = (const float*)d_in[2];
  const float* db = (const float*)d_in[3];
  const float* uw = (const float*)d_in[4];
  const float* ub = (const float*)d_in[5];
  const float* cw = (const float*)d_in[6];
  const float* cb = (const float*)d_in[7];
  const float* sw = (const float*)d_in[8];
  const float* sb = (const float*)d_in[9];
  float* out = (float*)d_out;

  char* ws = (char*)d_ws;
  float* fsum  = (float*)ws;                 // B*D
  float* xsum  = fsum + B_ * D_;             // B*SD
  float* flatw = xsum + B_ * SD_;            // B*E
  float* biasws = flatw + B_ * E_;           // B*D
  size_t off = (size_t)(B_ * D_ + B_ * SD_ + B_ * E_ + B_ * D_) * 4;
  off = (off + 255) & ~(size_t)255;
  u8* dwF8 = (u8*)(ws + off); off += (size_t)E_ * H_ * D_;
  u8* uwF8 = (u8*)(ws + off); off += (size_t)E_ * D_ * H_;
  const size_t need_lean = off;
  u8* F8 = (u8*)(ws + off); off += (size_t)B_ * S_ * D_;
  const size_t need_full = off;

  if (ws_size < need_lean) return;
  const bool lean = ws_size < need_full;

  hipMemsetAsync(d_ws, 0, (size_t)(B_ * D_ + B_ * SD_) * sizeof(float), stream);
  // dw [E][D=K][H=N] x16 ; uw [E][H=K][D=N] x16  (MX 32x32x64 frag layout)
  k_frag8mx<<<E_ * (D_ / 128) * (H_ / 32), 256, 0, stream>>>(dw, dwF8, D_, H_, 16.f);
  k_frag8mx<<<E_ * (H_ / 128) * (D_ / 32), 256, 0, stream>>>(uw, uwF8, H_, D_, 16.f);
  if (!lean) {
    k_convpool8<<<512, 256, 0, stream>>>(F, F8, fsum);
  } else {
    k_poolF<<<512, 256, 0, stream>>>(F, fsum);
  }
  k_xpool<<<B_, 256, 0, stream>>>(X, xsum);
  k_router<<<1, 256, 0, stream>>>(fsum, xsum, cw, cb, sw, sb, ub, flatw, biasws,
                                  out + (size_t)B_ * S_ * D_);
  if (!lean) {
    k_moe<0><<<1024, 512, 0, stream>>>(F8, F, dwF8, uwF8, db, flatw, biasws, out);
  } else {
    k_moe<1><<<1024, 512, 0, stream>>>(nullptr, F, dwF8, uwF8, db, flatw, biasws, out);
  }
}